// Round 1
// baseline (410.535 us; speedup 1.0000x reference)
//
#include <hip/hip_runtime.h>
#include <math.h>

#define EPSV 1e-5f

typedef __attribute__((ext_vector_type(8)))  short short8_t;
typedef __attribute__((ext_vector_type(16))) float f32x16;

static __device__ __forceinline__ short f2bf(float f) {
    union { float f; unsigned u; } v; v.f = f;
    unsigned r = (v.u + 0x7FFFu + ((v.u >> 16) & 1u)) >> 16;
    return (short)r;
}
static __device__ __forceinline__ unsigned pack2bf(float a, float b) {
    return (unsigned)(unsigned short)f2bf(a) | ((unsigned)(unsigned short)f2bf(b) << 16);
}
static __device__ __forceinline__ float bflo(unsigned u) {
    union { unsigned u; float f; } t; t.u = u << 16; return t.f;
}
static __device__ __forceinline__ float bfhi(unsigned u) {
    union { unsigned u; float f; } t; t.u = u & 0xffff0000u; return t.f;
}

// ---------------- prep: w_reg -> A2pack (k2 A-fragments), bf16 -------------------
__global__ void prep_A2(const float* __restrict__ w_reg, short* __restrict__ A2) {
    int gid = blockIdx.x * 256 + threadIdx.x;    // 73728 threads
    int l  = gid & 63;
    int ot = (gid >> 6) & 7;
    int s  = gid >> 9;
    int o  = ot * 32 + (l & 31);
    int tap = s >> 4;
    int cb  = (s & 15) * 16 + (l >> 5) * 8;
    short* dst = A2 + (size_t)gid * 8;
#pragma unroll
    for (int j = 0; j < 8; ++j)
        dst[j] = f2bf(w_reg[(o * 256 + cb + j) * 9 + tap]);
}

// ---------------- prep: w_off/w_mod -> A1 (k1 A-fragments), bf16 -----------------
__global__ void prep_A1(const float* __restrict__ w_off,
                        const float* __restrict__ w_mod, short* __restrict__ A1) {
    int gid = blockIdx.x * 256 + threadIdx.x;    // 9216 threads
    int l  = gid & 63;
    int s  = gid >> 6;          // 0..143
    int tap = s >> 4;
    int cq  = s & 15;
    int co  = l & 31;
    int cb  = cq * 16 + (l >> 5) * 8;
    short* dst = A1 + (size_t)gid * 8;
#pragma unroll
    for (int j = 0; j < 8; ++j) {
        int c = cb + j;
        float v = 0.f;
        if (co < 18)      v = w_off[(co * 256 + c) * 9 + tap];
        else if (co < 27) v = w_mod[((co - 18) * 256 + c) * 9 + tap];
        dst[j] = f2bf(v);
    }
}

// ---------------- prep: w_up -> Aup (k3 A-fragments), bf16 -----------------------
__global__ void prep_Aup(const float* __restrict__ w_up, short* __restrict__ Aup) {
    int gid = blockIdx.x * 256 + threadIdx.x;    // 131072 threads
    int l  = gid & 63;
    int ot = (gid >> 6) & 7;
    int s  = (gid >> 9) & 63;
    int sx = (gid >> 15) & 1;
    int sy = (gid >> 16) & 1;
    int chunk = s >> 4;
    int tap = (s >> 2) & 3;
    int ch  = s & 3;
    int ty = tap >> 1, tx = tap & 1;
    int o  = ot * 32 + (l & 31);
    int cb = chunk * 64 + ch * 16 + (l >> 5) * 8;
    int ky = (1 - sy) + 2 * ty;
    int kx = (1 - sx) + 2 * tx;
    short* dst = Aup + (size_t)gid * 8;
#pragma unroll
    for (int j = 0; j < 8; ++j)
        dst[j] = f2bf(w_up[((cb + j) * 256 + o) * 16 + ky * 4 + kx]);
}

// ---------------- k0: x (NCHW fp32) -> xT (NHWC bf16), 64x64 LDS tiles -----------
__global__ __launch_bounds__(256) void k0_nhwc(
    const float* __restrict__ x, unsigned short* __restrict__ xT) {
    __shared__ unsigned short t[64 * 65];
    int bx = blockIdx.x;
    int b   = bx & 7;
    int hwt = (bx >> 3) & 63;
    int ct  = bx >> 9;
    int tid = threadIdx.x;
    int g   = tid >> 6;
    int l   = tid & 63;
    const float* xb = x + ((size_t)b * 256 + ct * 64) * 4096 + hwt * 64;
#pragma unroll
    for (int i = 0; i < 16; ++i) {
        int c_l = g * 16 + i;
        t[c_l * 65 + l] = (unsigned short)f2bf(xb[(size_t)c_l * 4096 + l]);
    }
    __syncthreads();
    unsigned short* xo = xT + ((size_t)b * 4096 + hwt * 64) * 256 + ct * 64;
#pragma unroll
    for (int i = 0; i < 16; ++i) {
        int hw_l = g * 16 + i;
        xo[(size_t)hw_l * 256 + l] = t[l * 65 + hw_l];
    }
}

// ---------------- k1: offset+mask conv via bf16 MFMA -> offmask ------------------
__global__ __launch_bounds__(256, 2) void k1_mfma(
    const unsigned short* __restrict__ xT, const short* __restrict__ A1,
    const float* __restrict__ b_off, const float* __restrict__ b_mod,
    float* __restrict__ offmask) {
    __shared__ short xs[3 * 66 * 72];     // 28,512 B
    __shared__ float red[4][32][64];      // 32,768 B

    int bx = blockIdx.x;
    int b  = bx & 7;
    int h  = bx >> 3;
    int tid  = threadIdx.x;
    int lane = tid & 63;
    int wv   = tid >> 6;       // 0..3 (K-split)
    int ln = lane & 31;
    int lh = lane >> 5;

    if (tid < 192) {
        int r    = tid >> 6;
        int rest = tid & 63;
        int colp = (rest >> 5) * 65;
        int cd   = rest & 31;
        ((unsigned*)xs)[((r * 66 + colp) * 72 >> 1) + cd] = 0;
    }

    f32x16 acc[2];
#pragma unroll
    for (int pt = 0; pt < 2; ++pt)
#pragma unroll
        for (int r = 0; r < 16; ++r) acc[pt][r] = 0.f;

    const unsigned short* xTb = xT + (size_t)b * 4096 * 256;

    for (int cc = 0; cc < 256; cc += 64) {
#pragma unroll
        for (int it = 0; it < 6; ++it) {
            int e   = tid + it * 256;
            int ch8 = e & 7;             // 8-c chunk
            int col = (e >> 3) & 63;
            int r   = e >> 9;            // 0..2
            int row = h - 1 + r;
            bool v  = (row >= 0) & (row <= 63);
            short8_t val = {0,0,0,0,0,0,0,0};
            if (v) val = *(const short8_t*)(xTb + ((size_t)row * 64 + col) * 256 + cc + ch8 * 8);
            *(short8_t*)&xs[(r * 66 + col + 1) * 72 + ch8 * 8] = val;
        }
        __syncthreads();

#pragma unroll
        for (int tap = 0; tap < 9; ++tap) {
            int ky = tap / 3, kx = tap - 3 * (tap / 3);
            int s = tap * 16 + (cc >> 4) + wv;
            short8_t afr = *(const short8_t*)(A1 + ((size_t)s * 64 + lane) * 8);
            const short* bp = &xs[(ky * 66 + ln + kx) * 72 + wv * 16 + lh * 8];
            short8_t b0 = *(const short8_t*)bp;
            short8_t b1 = *(const short8_t*)(bp + 32 * 72);
            acc[0] = __builtin_amdgcn_mfma_f32_32x32x16_bf16(afr, b0, acc[0], 0, 0, 0);
            acc[1] = __builtin_amdgcn_mfma_f32_32x32x16_bf16(afr, b1, acc[1], 0, 0, 0);
        }
        __syncthreads();
    }

#pragma unroll
    for (int pt = 0; pt < 2; ++pt)
#pragma unroll
        for (int reg = 0; reg < 16; ++reg) {
            int row = (reg & 3) + 8 * (reg >> 2) + 4 * lh;
            red[wv][row][pt * 32 + ln] = acc[pt][reg];
        }
    __syncthreads();

    int pos = tid & 63;
    int cg  = tid >> 6;
#pragma unroll
    for (int i = 0; i < 7; ++i) {
        int co = 4 * i + cg;
        if (co < 27) {
            float sum = red[0][co][pos] + red[1][co][pos]
                      + red[2][co][pos] + red[3][co][pos];
            if (co < 18) {
                sum += b_off[co];
            } else {
                sum += b_mod[co - 18];
                sum = 2.f / (1.f + expf(-sum));
            }
            offmask[((size_t)(b * 27 + co) << 12) + (h << 6) + pos] = sum;
        }
    }
}

// ---------------- k2: deform sample (NHWC coalesced) + MFMA + bn1+relu -> h1 -----
__global__ __launch_bounds__(512, 4) void k2_deform(
    const unsigned short* __restrict__ xT, const float* __restrict__ offmask,
    const short* __restrict__ A2,
    const float* __restrict__ g1, const float* __restrict__ be1,
    const float* __restrict__ mu1, const float* __restrict__ va1,
    unsigned short* __restrict__ h1) {
    __shared__ unsigned short lds_v[64 * 264];   // [pos][c], pitch 264
    __shared__ int   sidx[9][64][4];
    __shared__ float swt [9][64][4];

    int bx = blockIdx.x;
    int b  = bx & 7;
    int h  = bx >> 3;
    int tid  = threadIdx.x;
    int lane = tid & 63;
    int wv   = tid >> 6;          // 0..7
    int ln = lane & 31;
    int lh = lane >> 5;

#pragma unroll
    for (int it = 0; it < 2; ++it) {
        int e = it * 512 + tid;
        if (e < 576) {
            int tap = e >> 6;
            int pos = e & 63;
            const float* om = offmask + ((size_t)b * 27 << 12) + (h << 6) + pos;
            float oy = om[(size_t)(2 * tap) << 12];
            float ox = om[(size_t)(2 * tap + 1) << 12];
            float m2 = om[(size_t)(18 + tap) << 12];
            int ky = tap / 3, kx = tap - 3 * (tap / 3);
            float py = (float)(h - 1 + ky) + oy;
            float px = (float)(pos - 1 + kx) + ox;
            float y0f = floorf(py), x0f = floorf(px);
            float wy1 = py - y0f, wy0 = 1.f - wy1;
            float wx1 = px - x0f, wx0 = 1.f - wx1;
            int y0 = (int)y0f, xq = (int)x0f;
            int y1 = y0 + 1, x1 = xq + 1;
            bool vy0 = (y0 >= 0) & (y0 < 64), vy1 = (y1 >= 0) & (y1 < 64);
            bool vx0 = (xq >= 0) & (xq < 64), vx1 = (x1 >= 0) & (x1 < 64);
            int y0c = min(max(y0, 0), 63), y1c = min(max(y1, 0), 63);
            int x0c = min(max(xq, 0), 63), x1c = min(max(x1, 0), 63);
            sidx[tap][pos][0] = y0c * 64 + x0c;  swt[tap][pos][0] = (vy0 && vx0) ? m2 * wy0 * wx0 : 0.f;
            sidx[tap][pos][1] = y0c * 64 + x1c;  swt[tap][pos][1] = (vy0 && vx1) ? m2 * wy0 * wx1 : 0.f;
            sidx[tap][pos][2] = y1c * 64 + x0c;  swt[tap][pos][2] = (vy1 && vx0) ? m2 * wy1 * wx0 : 0.f;
            sidx[tap][pos][3] = y1c * 64 + x1c;  swt[tap][pos][3] = (vy1 && vx1) ? m2 * wy1 * wx1 : 0.f;
        }
    }
    __syncthreads();

    f32x16 acc[2];
#pragma unroll
    for (int pt = 0; pt < 2; ++pt)
#pragma unroll
        for (int r = 0; r < 16; ++r) acc[pt][r] = 0.f;

    const unsigned* xTb = (const unsigned*)(xT + (size_t)b * 4096 * 256);

    for (int k = 0; k < 9; ++k) {
#pragma unroll
        for (int q = 0; q < 8; ++q) {
            int pos = wv * 8 + q;
            float a0 = 0.f, a1 = 0.f, a2 = 0.f, a3 = 0.f;
#pragma unroll
            for (int i = 0; i < 4; ++i) {
                int   idx = sidx[k][pos][i];
                float wt  = swt[k][pos][i];
                const unsigned* cp = xTb + ((size_t)idx << 7) + (lane << 1);
                unsigned u0 = cp[0], u1 = cp[1];
                a0 = fmaf(wt, bflo(u0), a0);
                a1 = fmaf(wt, bfhi(u0), a1);
                a2 = fmaf(wt, bflo(u1), a2);
                a3 = fmaf(wt, bfhi(u1), a3);
            }
            unsigned* dst = (unsigned*)&lds_v[pos * 264 + lane * 4];
            dst[0] = pack2bf(a0, a1);
            dst[1] = pack2bf(a2, a3);
        }
        __syncthreads();

#pragma unroll 4
        for (int sl = 0; sl < 16; ++sl) {
            int s = k * 16 + sl;
            short8_t afr = *(const short8_t*)(A2 + (((size_t)s * 8 + wv) * 64 + lane) * 8);
            short8_t b0 = *(const short8_t*)&lds_v[ln        * 264 + sl * 16 + lh * 8];
            short8_t b1 = *(const short8_t*)&lds_v[(32 + ln) * 264 + sl * 16 + lh * 8];
            acc[0] = __builtin_amdgcn_mfma_f32_32x32x16_bf16(afr, b0, acc[0], 0, 0, 0);
            acc[1] = __builtin_amdgcn_mfma_f32_32x32x16_bf16(afr, b1, acc[1], 0, 0, 0);
        }
        __syncthreads();
    }

#pragma unroll
    for (int reg = 0; reg < 16; ++reg) {
        int o = wv * 32 + (reg & 3) + 8 * (reg >> 2) + 4 * lh;
        float sc = g1[o] / sqrtf(va1[o] + EPSV);
        float sh = be1[o] - mu1[o] * sc;
        size_t ob = ((size_t)(b * 256 + o) * 64 + h) * 64;
#pragma unroll
        for (int pt = 0; pt < 2; ++pt) {
            float v = fmaxf(fmaf(acc[pt][reg], sc, sh), 0.f);
            h1[ob + pt * 32 + ln] = (unsigned short)f2bf(v);
        }
    }
}

// ---------------- k3: conv_transpose via bf16 MFMA, R=2 row-blocked --------------
// Block = (b, sy, m-pair). Each block computes output rows y=2*(m0+r)+sy, r=0..1,
// all 256 o, all 128 x. Stages 3 h1 source rows (m0+sy-1 .. m0+sy+1) per 64-c
// chunk. Each A-fragment (Aup, L2-resident) now feeds 8 MFMA (i=2 o-tiles x
// r=2 rows x mh=2 pos-halves) instead of 4 -> halves the 1 GB A-operand L2
// stream that co-limited the previous version. 128 acc regs/wave -> 2 waves/SIMD.
__global__ __launch_bounds__(512, 2) void k3_convt(
    const unsigned short* __restrict__ h1, const short* __restrict__ Aup,
    const float* __restrict__ g2, const float* __restrict__ be2,
    const float* __restrict__ mu2, const float* __restrict__ va2,
    float* __restrict__ out) {
    __shared__ short lds[3 * 66 * 72];   // 28,512 B

    int bx = blockIdx.x;
    int b  = bx & 7;
    int sy = (bx >> 3) & 1;
    int m0 = (bx >> 4) * 2;      // 0,2,...,62
    int tid  = threadIdx.x;
    int lane = tid & 63;
    int wv   = tid >> 6;         // 0..7
    int ow = wv & 3;
    int sx = wv >> 2;
    int ln = lane & 31;
    int lh = lane >> 5;
    int col = lane;              // staging column

    int rbase = m0 + sy - 1;     // staged source rows rbase..rbase+2

    // zero halo columns (phys col 0 and 65), 3 rows, 64 c (32 dwords each)
    if (tid < 192) {
        int r    = tid >> 6;
        int rest = tid & 63;
        int colp = (rest >> 5) * 65;
        int cd   = rest & 31;
        ((unsigned*)lds)[((r * 66 + colp) * 72 >> 1) + cd] = 0;
    }

    f32x16 acc[2][2][2];         // [i o-tile][r row][mh pos-half]
#pragma unroll
    for (int i = 0; i < 2; ++i)
#pragma unroll
        for (int r = 0; r < 2; ++r)
#pragma unroll
            for (int mh = 0; mh < 2; ++mh)
#pragma unroll
                for (int e = 0; e < 16; ++e) acc[i][r][mh][e] = 0.f;

    const unsigned short* hb = h1 + (size_t)b * 256 * 4096;
    // per-(sy,sx) variant; slot=ow for a0, ow+4 for a1 (slot stride 512 shorts)
    const short* Abase = Aup + (size_t)(sy * 2 + sx) * 262144 + ow * 512 + lane * 8;

    for (int cc = 0; cc < 256; cc += 64) {
        // stage 3 rows x 64 cols x 64 c (4-ch quads), 6 its x 512 thr
#pragma unroll
        for (int it = 0; it < 6; ++it) {
            int quad = ((tid >> 6) & 7) + (it & 1) * 8;   // 0..15
            int r    = it >> 1;                            // 0..2
            int row  = rbase + r;
            bool v   = (row >= 0) & (row <= 63);
            int cb   = cc + quad * 4;
            unsigned short u0 = v ? hb[(size_t)(cb + 0) * 4096 + row * 64 + col] : (unsigned short)0;
            unsigned short u1 = v ? hb[(size_t)(cb + 1) * 4096 + row * 64 + col] : (unsigned short)0;
            unsigned short u2 = v ? hb[(size_t)(cb + 2) * 4096 + row * 64 + col] : (unsigned short)0;
            unsigned short u3 = v ? hb[(size_t)(cb + 3) * 4096 + row * 64 + col] : (unsigned short)0;
            unsigned* dst = (unsigned*)&lds[(r * 66 + col + 1) * 72 + quad * 4];
            dst[0] = (unsigned)u0 | ((unsigned)u1 << 16);
            dst[1] = (unsigned)u2 | ((unsigned)u3 << 16);
        }
        __syncthreads();

#pragma unroll
        for (int st = 0; st < 16; ++st) {
            int tap = st >> 2;
            int ch  = st & 3;
            int ty = tap >> 1, tx = tap & 1;
            int s_g = (cc >> 2) + st;
            short8_t a0 = *(const short8_t*)(Abase + (size_t)s_g * 4096);
            short8_t a1 = *(const short8_t*)(Abase + (size_t)s_g * 4096 + 2048);
#pragma unroll
            for (int r = 0; r < 2; ++r) {
                // output row m0+r: ty=0 uses staged row r+1, ty=1 uses staged row r
                int cbase = (r + 1 - ty) * 66 + ln + sx - tx + 1;
                short8_t b0 = *(const short8_t*)&lds[cbase * 72 + ch * 16 + lh * 8];
                short8_t b1 = *(const short8_t*)&lds[(cbase + 32) * 72 + ch * 16 + lh * 8];
                acc[0][r][0] = __builtin_amdgcn_mfma_f32_32x32x16_bf16(a0, b0, acc[0][r][0], 0, 0, 0);
                acc[0][r][1] = __builtin_amdgcn_mfma_f32_32x32x16_bf16(a0, b1, acc[0][r][1], 0, 0, 0);
                acc[1][r][0] = __builtin_amdgcn_mfma_f32_32x32x16_bf16(a1, b0, acc[1][r][0], 0, 0, 0);
                acc[1][r][1] = __builtin_amdgcn_mfma_f32_32x32x16_bf16(a1, b1, acc[1][r][1], 0, 0, 0);
            }
        }
        __syncthreads();
    }

#pragma unroll
    for (int i = 0; i < 2; ++i) {
#pragma unroll
        for (int reg = 0; reg < 16; ++reg) {
            int o = (ow + 4 * i) * 32 + (reg & 3) + 8 * (reg >> 2) + 4 * lh;
            float sc = g2[o] / sqrtf(va2[o] + EPSV);
            float sh = be2[o] - mu2[o] * sc;
#pragma unroll
            for (int r = 0; r < 2; ++r) {
                int y = 2 * (m0 + r) + sy;
                size_t ob = ((size_t)(b * 256 + o) * 128 + y) * 128;
#pragma unroll
                for (int mh = 0; mh < 2; ++mh) {
                    int x = 2 * (mh * 32 + ln) + sx;
                    out[ob + x] = fmaxf(fmaf(acc[i][r][mh][reg], sc, sh), 0.f);
                }
            }
        }
    }
}

extern "C" void kernel_launch(void* const* d_in, const int* in_sizes, int n_in,
                              void* d_out, int out_size, void* d_ws, size_t ws_size,
                              hipStream_t stream) {
    const float* x      = (const float*)d_in[0];
    const float* w_off  = (const float*)d_in[1];
    const float* b_off  = (const float*)d_in[2];
    const float* w_mod  = (const float*)d_in[3];
    const float* b_mod  = (const float*)d_in[4];
    const float* w_reg  = (const float*)d_in[5];
    const float* g1     = (const float*)d_in[6];
    const float* be1    = (const float*)d_in[7];
    const float* mu1    = (const float*)d_in[8];
    const float* va1    = (const float*)d_in[9];
    const float* w_up   = (const float*)d_in[10];
    const float* g2     = (const float*)d_in[11];
    const float* be2    = (const float*)d_in[12];
    const float* mu2    = (const float*)d_in[13];
    const float* va2    = (const float*)d_in[14];

    float* ws      = (float*)d_ws;
    float* offmask = ws;                                     //   884,736 f
    short* A2      = (short*)(offmask + 884736);             //   589,824 sh
    short* A1      = A2 + 589824;                            //    73,728 sh
    short* Aup     = A1 + 73728;                             // 1,048,576 sh
    unsigned short* h1 = (unsigned short*)(Aup + 1048576);   // 8,388,608 sh
    unsigned short* xT = h1 + 8388608;                       // 8,388,608 sh

    prep_A2   <<<288,  256, 0, stream>>>(w_reg, A2);
    prep_A1   <<<36,   256, 0, stream>>>(w_off, w_mod, A1);
    prep_Aup  <<<512,  256, 0, stream>>>(w_up, Aup);
    k0_nhwc   <<<2048, 256, 0, stream>>>(x, xT);
    k1_mfma   <<<512,  256, 0, stream>>>(xT, A1, b_off, b_mod, offmask);
    k2_deform <<<512,  512, 0, stream>>>(xT, offmask, A2, g1, be1, mu1, va1, h1);
    k3_convt  <<<512,  512, 0, stream>>>(h1, Aup, g2, be2, mu2, va2, (float*)d_out);
}

// Round 2
// 392.334 us; speedup vs baseline: 1.0464x; 1.0464x over previous
//
#include <hip/hip_runtime.h>
#include <math.h>

#define EPSV 1e-5f

typedef __attribute__((ext_vector_type(8)))  short short8_t;
typedef __attribute__((ext_vector_type(16))) float f32x16;

static __device__ __forceinline__ short f2bf(float f) {
    union { float f; unsigned u; } v; v.f = f;
    unsigned r = (v.u + 0x7FFFu + ((v.u >> 16) & 1u)) >> 16;
    return (short)r;
}
static __device__ __forceinline__ unsigned pack2bf(float a, float b) {
    return (unsigned)(unsigned short)f2bf(a) | ((unsigned)(unsigned short)f2bf(b) << 16);
}
static __device__ __forceinline__ float bflo(unsigned u) {
    union { unsigned u; float f; } t; t.u = u << 16; return t.f;
}
static __device__ __forceinline__ float bfhi(unsigned u) {
    union { unsigned u; float f; } t; t.u = u & 0xffff0000u; return t.f;
}

// ---------------- prep: w_reg -> A2pack (k2 A-fragments), bf16 -------------------
__global__ void prep_A2(const float* __restrict__ w_reg, short* __restrict__ A2) {
    int gid = blockIdx.x * 256 + threadIdx.x;    // 73728 threads
    int l  = gid & 63;
    int ot = (gid >> 6) & 7;
    int s  = gid >> 9;
    int o  = ot * 32 + (l & 31);
    int tap = s >> 4;
    int cb  = (s & 15) * 16 + (l >> 5) * 8;
    short* dst = A2 + (size_t)gid * 8;
#pragma unroll
    for (int j = 0; j < 8; ++j)
        dst[j] = f2bf(w_reg[(o * 256 + cb + j) * 9 + tap]);
}

// ---------------- prep: w_off/w_mod -> A1 (k1 A-fragments), bf16 -----------------
__global__ void prep_A1(const float* __restrict__ w_off,
                        const float* __restrict__ w_mod, short* __restrict__ A1) {
    int gid = blockIdx.x * 256 + threadIdx.x;    // 9216 threads
    int l  = gid & 63;
    int s  = gid >> 6;          // 0..143
    int tap = s >> 4;
    int cq  = s & 15;
    int co  = l & 31;
    int cb  = cq * 16 + (l >> 5) * 8;
    short* dst = A1 + (size_t)gid * 8;
#pragma unroll
    for (int j = 0; j < 8; ++j) {
        int c = cb + j;
        float v = 0.f;
        if (co < 18)      v = w_off[(co * 256 + c) * 9 + tap];
        else if (co < 27) v = w_mod[((co - 18) * 256 + c) * 9 + tap];
        dst[j] = f2bf(v);
    }
}

// ---------------- prep: w_up -> Aup (k3 A-fragments), bf16 -----------------------
__global__ void prep_Aup(const float* __restrict__ w_up, short* __restrict__ Aup) {
    int gid = blockIdx.x * 256 + threadIdx.x;    // 131072 threads
    int l  = gid & 63;
    int ot = (gid >> 6) & 7;
    int s  = (gid >> 9) & 63;
    int sx = (gid >> 15) & 1;
    int sy = (gid >> 16) & 1;
    int chunk = s >> 4;
    int tap = (s >> 2) & 3;
    int ch  = s & 3;
    int ty = tap >> 1, tx = tap & 1;
    int o  = ot * 32 + (l & 31);
    int cb = chunk * 64 + ch * 16 + (l >> 5) * 8;
    int ky = (1 - sy) + 2 * ty;
    int kx = (1 - sx) + 2 * tx;
    short* dst = Aup + (size_t)gid * 8;
#pragma unroll
    for (int j = 0; j < 8; ++j)
        dst[j] = f2bf(w_up[((cb + j) * 256 + o) * 16 + ky * 4 + kx]);
}

// ---------------- k0: x (NCHW fp32) -> xT (NHWC bf16), 64x64 LDS tiles -----------
__global__ __launch_bounds__(256) void k0_nhwc(
    const float* __restrict__ x, unsigned short* __restrict__ xT) {
    __shared__ unsigned short t[64 * 65];
    int bx = blockIdx.x;
    int b   = bx & 7;
    int hwt = (bx >> 3) & 63;
    int ct  = bx >> 9;
    int tid = threadIdx.x;
    int g   = tid >> 6;
    int l   = tid & 63;
    const float* xb = x + ((size_t)b * 256 + ct * 64) * 4096 + hwt * 64;
#pragma unroll
    for (int i = 0; i < 16; ++i) {
        int c_l = g * 16 + i;
        t[c_l * 65 + l] = (unsigned short)f2bf(xb[(size_t)c_l * 4096 + l]);
    }
    __syncthreads();
    unsigned short* xo = xT + ((size_t)b * 4096 + hwt * 64) * 256 + ct * 64;
#pragma unroll
    for (int i = 0; i < 16; ++i) {
        int hw_l = g * 16 + i;
        xo[(size_t)hw_l * 256 + l] = t[l * 65 + hw_l];
    }
}

// ---------------- k1: offset+mask conv via bf16 MFMA -> offmask ------------------
__global__ __launch_bounds__(256, 2) void k1_mfma(
    const unsigned short* __restrict__ xT, const short* __restrict__ A1,
    const float* __restrict__ b_off, const float* __restrict__ b_mod,
    float* __restrict__ offmask) {
    __shared__ short xs[3 * 66 * 72];     // 28,512 B
    __shared__ float red[4][32][64];      // 32,768 B

    int bx = blockIdx.x;
    int b  = bx & 7;
    int h  = bx >> 3;
    int tid  = threadIdx.x;
    int lane = tid & 63;
    int wv   = tid >> 6;       // 0..3 (K-split)
    int ln = lane & 31;
    int lh = lane >> 5;

    if (tid < 192) {
        int r    = tid >> 6;
        int rest = tid & 63;
        int colp = (rest >> 5) * 65;
        int cd   = rest & 31;
        ((unsigned*)xs)[((r * 66 + colp) * 72 >> 1) + cd] = 0;
    }

    f32x16 acc[2];
#pragma unroll
    for (int pt = 0; pt < 2; ++pt)
#pragma unroll
        for (int r = 0; r < 16; ++r) acc[pt][r] = 0.f;

    const unsigned short* xTb = xT + (size_t)b * 4096 * 256;

    for (int cc = 0; cc < 256; cc += 64) {
#pragma unroll
        for (int it = 0; it < 6; ++it) {
            int e   = tid + it * 256;
            int ch8 = e & 7;             // 8-c chunk
            int col = (e >> 3) & 63;
            int r   = e >> 9;            // 0..2
            int row = h - 1 + r;
            bool v  = (row >= 0) & (row <= 63);
            short8_t val = {0,0,0,0,0,0,0,0};
            if (v) val = *(const short8_t*)(xTb + ((size_t)row * 64 + col) * 256 + cc + ch8 * 8);
            *(short8_t*)&xs[(r * 66 + col + 1) * 72 + ch8 * 8] = val;
        }
        __syncthreads();

#pragma unroll
        for (int tap = 0; tap < 9; ++tap) {
            int ky = tap / 3, kx = tap - 3 * (tap / 3);
            int s = tap * 16 + (cc >> 4) + wv;
            short8_t afr = *(const short8_t*)(A1 + ((size_t)s * 64 + lane) * 8);
            const short* bp = &xs[(ky * 66 + ln + kx) * 72 + wv * 16 + lh * 8];
            short8_t b0 = *(const short8_t*)bp;
            short8_t b1 = *(const short8_t*)(bp + 32 * 72);
            acc[0] = __builtin_amdgcn_mfma_f32_32x32x16_bf16(afr, b0, acc[0], 0, 0, 0);
            acc[1] = __builtin_amdgcn_mfma_f32_32x32x16_bf16(afr, b1, acc[1], 0, 0, 0);
        }
        __syncthreads();
    }

#pragma unroll
    for (int pt = 0; pt < 2; ++pt)
#pragma unroll
        for (int reg = 0; reg < 16; ++reg) {
            int row = (reg & 3) + 8 * (reg >> 2) + 4 * lh;
            red[wv][row][pt * 32 + ln] = acc[pt][reg];
        }
    __syncthreads();

    int pos = tid & 63;
    int cg  = tid >> 6;
#pragma unroll
    for (int i = 0; i < 7; ++i) {
        int co = 4 * i + cg;
        if (co < 27) {
            float sum = red[0][co][pos] + red[1][co][pos]
                      + red[2][co][pos] + red[3][co][pos];
            if (co < 18) {
                sum += b_off[co];
            } else {
                sum += b_mod[co - 18];
                sum = 2.f / (1.f + expf(-sum));
            }
            offmask[((size_t)(b * 27 + co) << 12) + (h << 6) + pos] = sum;
        }
    }
}

// ---------------- k2: deform sample (NHWC coalesced) + MFMA + bn1+relu -> h1 -----
__global__ __launch_bounds__(512, 4) void k2_deform(
    const unsigned short* __restrict__ xT, const float* __restrict__ offmask,
    const short* __restrict__ A2,
    const float* __restrict__ g1, const float* __restrict__ be1,
    const float* __restrict__ mu1, const float* __restrict__ va1,
    unsigned short* __restrict__ h1) {
    __shared__ unsigned short lds_v[64 * 264];   // [pos][c], pitch 264
    __shared__ int   sidx[9][64][4];
    __shared__ float swt [9][64][4];

    int bx = blockIdx.x;
    int b  = bx & 7;
    int h  = bx >> 3;
    int tid  = threadIdx.x;
    int lane = tid & 63;
    int wv   = tid >> 6;          // 0..7
    int ln = lane & 31;
    int lh = lane >> 5;

#pragma unroll
    for (int it = 0; it < 2; ++it) {
        int e = it * 512 + tid;
        if (e < 576) {
            int tap = e >> 6;
            int pos = e & 63;
            const float* om = offmask + ((size_t)b * 27 << 12) + (h << 6) + pos;
            float oy = om[(size_t)(2 * tap) << 12];
            float ox = om[(size_t)(2 * tap + 1) << 12];
            float m2 = om[(size_t)(18 + tap) << 12];
            int ky = tap / 3, kx = tap - 3 * (tap / 3);
            float py = (float)(h - 1 + ky) + oy;
            float px = (float)(pos - 1 + kx) + ox;
            float y0f = floorf(py), x0f = floorf(px);
            float wy1 = py - y0f, wy0 = 1.f - wy1;
            float wx1 = px - x0f, wx0 = 1.f - wx1;
            int y0 = (int)y0f, xq = (int)x0f;
            int y1 = y0 + 1, x1 = xq + 1;
            bool vy0 = (y0 >= 0) & (y0 < 64), vy1 = (y1 >= 0) & (y1 < 64);
            bool vx0 = (xq >= 0) & (xq < 64), vx1 = (x1 >= 0) & (x1 < 64);
            int y0c = min(max(y0, 0), 63), y1c = min(max(y1, 0), 63);
            int x0c = min(max(xq, 0), 63), x1c = min(max(x1, 0), 63);
            sidx[tap][pos][0] = y0c * 64 + x0c;  swt[tap][pos][0] = (vy0 && vx0) ? m2 * wy0 * wx0 : 0.f;
            sidx[tap][pos][1] = y0c * 64 + x1c;  swt[tap][pos][1] = (vy0 && vx1) ? m2 * wy0 * wx1 : 0.f;
            sidx[tap][pos][2] = y1c * 64 + x0c;  swt[tap][pos][2] = (vy1 && vx0) ? m2 * wy1 * wx0 : 0.f;
            sidx[tap][pos][3] = y1c * 64 + x1c;  swt[tap][pos][3] = (vy1 && vx1) ? m2 * wy1 * wx1 : 0.f;
        }
    }
    __syncthreads();

    f32x16 acc[2];
#pragma unroll
    for (int pt = 0; pt < 2; ++pt)
#pragma unroll
        for (int r = 0; r < 16; ++r) acc[pt][r] = 0.f;

    const unsigned* xTb = (const unsigned*)(xT + (size_t)b * 4096 * 256);

    for (int k = 0; k < 9; ++k) {
#pragma unroll
        for (int q = 0; q < 8; ++q) {
            int pos = wv * 8 + q;
            float a0 = 0.f, a1 = 0.f, a2 = 0.f, a3 = 0.f;
#pragma unroll
            for (int i = 0; i < 4; ++i) {
                int   idx = sidx[k][pos][i];
                float wt  = swt[k][pos][i];
                const unsigned* cp = xTb + ((size_t)idx << 7) + (lane << 1);
                unsigned u0 = cp[0], u1 = cp[1];
                a0 = fmaf(wt, bflo(u0), a0);
                a1 = fmaf(wt, bfhi(u0), a1);
                a2 = fmaf(wt, bflo(u1), a2);
                a3 = fmaf(wt, bfhi(u1), a3);
            }
            unsigned* dst = (unsigned*)&lds_v[pos * 264 + lane * 4];
            dst[0] = pack2bf(a0, a1);
            dst[1] = pack2bf(a2, a3);
        }
        __syncthreads();

#pragma unroll 4
        for (int sl = 0; sl < 16; ++sl) {
            int s = k * 16 + sl;
            short8_t afr = *(const short8_t*)(A2 + (((size_t)s * 8 + wv) * 64 + lane) * 8);
            short8_t b0 = *(const short8_t*)&lds_v[ln        * 264 + sl * 16 + lh * 8];
            short8_t b1 = *(const short8_t*)&lds_v[(32 + ln) * 264 + sl * 16 + lh * 8];
            acc[0] = __builtin_amdgcn_mfma_f32_32x32x16_bf16(afr, b0, acc[0], 0, 0, 0);
            acc[1] = __builtin_amdgcn_mfma_f32_32x32x16_bf16(afr, b1, acc[1], 0, 0, 0);
        }
        __syncthreads();
    }

#pragma unroll
    for (int reg = 0; reg < 16; ++reg) {
        int o = wv * 32 + (reg & 3) + 8 * (reg >> 2) + 4 * lh;
        float sc = g1[o] / sqrtf(va1[o] + EPSV);
        float sh = be1[o] - mu1[o] * sc;
        size_t ob = ((size_t)(b * 256 + o) * 64 + h) * 64;
#pragma unroll
        for (int pt = 0; pt < 2; ++pt) {
            float v = fmaxf(fmaf(acc[pt][reg], sc, sh), 0.f);
            h1[ob + pt * 32 + ln] = (unsigned short)f2bf(v);
        }
    }
}

// ---------------- k3: conv_transpose via bf16 MFMA, pipelined R=1 ----------------
// Reverted to 1024-block R=1 geometry (regression post-mortem: R=2 was latency-
// bound at 1 block/CU). Pipeline: double-buffered B-LDS, ONE barrier per 64-c
// chunk; next chunk's 16 staging loads issued before current chunk's MFMA phase
// (T14 issue-early/write-late); Aup fragments prefetched depth-2 in regs so the
// in-loop L2 latency is off the critical path; setprio(1) around MFMA cluster.
__global__ __launch_bounds__(512, 4) void k3_convt(
    const unsigned short* __restrict__ h1, const short* __restrict__ Aup,
    const float* __restrict__ g2, const float* __restrict__ be2,
    const float* __restrict__ mu2, const float* __restrict__ va2,
    float* __restrict__ out) {
    __shared__ short lds[2][2 * 66 * 72];   // 2 x 19,008 B

    int bx = blockIdx.x;
    int b  = bx & 7;
    int y  = bx >> 3;            // 0..127
    int sy = y & 1;
    int m  = y >> 1;
    int tid  = threadIdx.x;
    int lane = tid & 63;
    int wv   = tid >> 6;
    int ow = wv & 3;
    int sx = wv >> 2;
    int ln = lane & 31;
    int lh = lane >> 5;
    int col = tid & 63;

    int row0 = m + sy;           // ty=0 source row
    int row1 = row0 - 1;         // ty=1 source row
    bool v0 = (row0 <= 63);
    bool v1 = (row1 >= 0);

    // zero halo columns (phys col 0 and 65), both buffers
    if (tid < 288) {
        int r  = tid / 144;
        int rm = tid - r * 144;
        int cp = (rm / 72) * 65;
        int cz = rm - (rm / 72) * 72;
#pragma unroll
        for (int bi = 0; bi < 2; ++bi)
            lds[bi][(r * 66 + cp) * 72 + cz] = 0;
    }

    f32x16 acc[2][2];            // [o-tile i][mh]
#pragma unroll
    for (int i = 0; i < 2; ++i)
#pragma unroll
        for (int mh = 0; mh < 2; ++mh)
#pragma unroll
            for (int r = 0; r < 16; ++r) acc[i][mh][r] = 0.f;

    const unsigned short* hb = h1 + (size_t)b * 256 * 4096;
    // fold lane/ow into base; a0 at +s_g*4096, a1 at +s_g*4096+2048
    const short* Abase = Aup + (size_t)(sy * 2 + sx) * 262144 + ow * 512 + lane * 8;

    unsigned short uS[4][4];     // staged chunk held in regs (issue-early)

#define LOADC(CC) {                                                          \
    _Pragma("unroll")                                                        \
    for (int it = 0; it < 4; ++it) {                                         \
        int quad = ((tid >> 6) & 7) + (it & 1) * 8;                          \
        int r    = it >> 1;                                                  \
        int row  = r ? row1 : row0;                                          \
        bool v   = r ? v1 : v0;                                              \
        int cb   = (CC) + quad * 4;                                          \
        const unsigned short* p = hb + (size_t)cb * 4096 + row * 64 + col;   \
        uS[it][0] = v ? p[0]     : (unsigned short)0;                        \
        uS[it][1] = v ? p[4096]  : (unsigned short)0;                        \
        uS[it][2] = v ? p[8192]  : (unsigned short)0;                        \
        uS[it][3] = v ? p[12288] : (unsigned short)0;                        \
    } }

#define WRITEC(L) {                                                         \
    _Pragma("unroll")                                                       \
    for (int it = 0; it < 4; ++it) {                                        \
        int quad = ((tid >> 6) & 7) + (it & 1) * 8;                         \
        int r    = it >> 1;                                                 \
        unsigned* dst = (unsigned*)&(L)[(r * 66 + col + 1) * 72 + quad * 4];\
        dst[0] = (unsigned)uS[it][0] | ((unsigned)uS[it][1] << 16);         \
        dst[1] = (unsigned)uS[it][2] | ((unsigned)uS[it][3] << 16);         \
    } }

    LOADC(0);
    WRITEC(lds[0]);
    LOADC(64);                  // chunk 1 in flight across chunk 0's MFMA phase
    __syncthreads();            // lds[0] ready (halo zeros included)

    for (int cc = 0; cc < 256; cc += 64) {
        int cur = (cc >> 6) & 1;
        const short* L = lds[cur];

        // A-fragment depth-2 register prefetch
        const short* Ac = Abase + (size_t)(cc >> 2) * 4096;
        short8_t aA0 = *(const short8_t*)(Ac);
        short8_t aA1 = *(const short8_t*)(Ac + 2048);
        short8_t aB0 = *(const short8_t*)(Ac + 4096);
        short8_t aB1 = *(const short8_t*)(Ac + 4096 + 2048);

        __builtin_amdgcn_s_setprio(1);
#pragma unroll
        for (int st = 0; st < 16; ++st) {
            int tap = st >> 2;
            int ch  = st & 3;
            int ty = tap >> 1, tx = tap & 1;
            short8_t c0 = (st & 1) ? aB0 : aA0;
            short8_t c1 = (st & 1) ? aB1 : aA1;
            if (st < 14) {
                const short* an = Ac + (size_t)(st + 2) * 4096;
                if (st & 1) { aB0 = *(const short8_t*)an; aB1 = *(const short8_t*)(an + 2048); }
                else        { aA0 = *(const short8_t*)an; aA1 = *(const short8_t*)(an + 2048); }
            }
            int cbase = ty * 66 + ln + sx - tx + 1;
            short8_t b0 = *(const short8_t*)&L[cbase * 72 + ch * 16 + lh * 8];
            short8_t b1 = *(const short8_t*)&L[(cbase + 32) * 72 + ch * 16 + lh * 8];
            acc[0][0] = __builtin_amdgcn_mfma_f32_32x32x16_bf16(c0, b0, acc[0][0], 0, 0, 0);
            acc[0][1] = __builtin_amdgcn_mfma_f32_32x32x16_bf16(c0, b1, acc[0][1], 0, 0, 0);
            acc[1][0] = __builtin_amdgcn_mfma_f32_32x32x16_bf16(c1, b0, acc[1][0], 0, 0, 0);
            acc[1][1] = __builtin_amdgcn_mfma_f32_32x32x16_bf16(c1, b1, acc[1][1], 0, 0, 0);
        }
        __builtin_amdgcn_s_setprio(0);

        if (cc < 192) {
            WRITEC(lds[cur ^ 1]);            // regs already landed (issued a phase ago)
            if (cc < 128) LOADC(cc + 128);   // issue chunk cc/64+2
            __syncthreads();                 // next buffer ready; current reads drained
        }
    }

#undef LOADC
#undef WRITEC

#pragma unroll
    for (int i = 0; i < 2; ++i) {
#pragma unroll
        for (int reg = 0; reg < 16; ++reg) {
            int o = (ow + 4 * i) * 32 + (reg & 3) + 8 * (reg >> 2) + 4 * lh;
            float sc = g2[o] / sqrtf(va2[o] + EPSV);
            float sh = be2[o] - mu2[o] * sc;
            size_t ob = ((size_t)(b * 256 + o) * 128 + y) * 128;
#pragma unroll
            for (int mh = 0; mh < 2; ++mh) {
                int x = 2 * (mh * 32 + ln) + sx;
                out[ob + x] = fmaxf(fmaf(acc[i][mh][reg], sc, sh), 0.f);
            }
        }
    }
}

extern "C" void kernel_launch(void* const* d_in, const int* in_sizes, int n_in,
                              void* d_out, int out_size, void* d_ws, size_t ws_size,
                              hipStream_t stream) {
    const float* x      = (const float*)d_in[0];
    const float* w_off  = (const float*)d_in[1];
    const float* b_off  = (const float*)d_in[2];
    const float* w_mod  = (const float*)d_in[3];
    const float* b_mod  = (const float*)d_in[4];
    const float* w_reg  = (const float*)d_in[5];
    const float* g1     = (const float*)d_in[6];
    const float* be1    = (const float*)d_in[7];
    const float* mu1    = (const float*)d_in[8];
    const float* va1    = (const float*)d_in[9];
    const float* w_up   = (const float*)d_in[10];
    const float* g2     = (const float*)d_in[11];
    const float* be2    = (const float*)d_in[12];
    const float* mu2    = (const float*)d_in[13];
    const float* va2    = (const float*)d_in[14];

    float* ws      = (float*)d_ws;
    float* offmask = ws;                                     //   884,736 f
    short* A2      = (short*)(offmask + 884736);             //   589,824 sh
    short* A1      = A2 + 589824;                            //    73,728 sh
    short* Aup     = A1 + 73728;                             // 1,048,576 sh
    unsigned short* h1 = (unsigned short*)(Aup + 1048576);   // 8,388,608 sh
    unsigned short* xT = h1 + 8388608;                       // 8,388,608 sh

    prep_A2   <<<288,  256, 0, stream>>>(w_reg, A2);
    prep_A1   <<<36,   256, 0, stream>>>(w_off, w_mod, A1);
    prep_Aup  <<<512,  256, 0, stream>>>(w_up, Aup);
    k0_nhwc   <<<2048, 256, 0, stream>>>(x, xT);
    k1_mfma   <<<512,  256, 0, stream>>>(xT, A1, b_off, b_mod, offmask);
    k2_deform <<<512,  512, 0, stream>>>(xT, offmask, A2, g1, be1, mu1, va1, h1);
    k3_convt  <<<1024, 512, 0, stream>>>(h1, Aup, g2, be2, mu2, va2, (float*)d_out);
}